// Round 9
// baseline (116.071 us; speedup 1.0000x reference)
//
#include <hip/hip_runtime.h>
#include <hip/hip_bf16.h>

#define PIX 256
#define CROP 14
#define HW2 196
#define BB 128
#define CC 512
#define NC 384
#define NO 768
#define CAP 128

typedef __bf16 bf16x8 __attribute__((ext_vector_type(8)));
typedef __bf16 bf16x4 __attribute__((ext_vector_type(4)));
typedef float  f32x4  __attribute__((ext_vector_type(4)));
typedef unsigned int u32;

#define GLOAD_LDS16(src, dst) \
    __builtin_amdgcn_global_load_lds((const __attribute__((address_space(1))) void*)(src), \
                                     (__attribute__((address_space(3))) void*)(dst), 16, 0, 0)

__global__ void wconv_kernel(const float* __restrict__ W, __bf16* __restrict__ Wb) {
    int tid = blockIdx.x * 256 + threadIdx.x;
    Wb[tid] = (__bf16)W[tid];
}

// bucket word: ((c3*196+hw) << 8) | p
__global__ void fill_kernel(const int* __restrict__ idx, const int* __restrict__ offh,
                            const int* __restrict__ offw, int* __restrict__ cnt,
                            u32* __restrict__ bucket) {
    int tid = blockIdx.x * 256 + threadIdx.x;
    int c3 = tid / HW2;
    int hw = tid - c3 * HW2;
    int i = hw / CROP, j = hw - i * CROP;
    int p = (offh[c3] + i) * 16 + offw[c3] + j;
    int ch = idx[c3 * PIX + p];
    int bkt = (c3 >> 7) * CC + ch;
    int pos = atomicAdd(&cnt[bkt], 1);
    if (pos < CAP) bucket[bkt * CAP + pos] = ((u32)tid << 8) | (u32)p;
}

// scatter v5: block = (t, ch-QUAD) x 16 b-rows. Global reads are 16 chunks of
// 4KB CONTIGUOUS (rows b,ch..ch+3 are adjacent in x) — 4x the contiguity of v4
// at identical DMA count/width/bytes. LDS [r][q][p-swz] with 16B-chunk XOR
// swizzle (chunk ^ r) pre-applied to the DMA source (linear LDS dest, rule 21);
// scatter read lanes r=0..15 then spread across banks 2-way (free).
__global__ __launch_bounds__(256) void scatter_kernel(
        const float* __restrict__ x1, const float* __restrict__ x3,
        const float* __restrict__ x5, const int* __restrict__ cnt,
        const u32* __restrict__ bucket, __bf16* __restrict__ fT) {
    __shared__ float ldsf[16 * 4 * 256];   // 64 KB: [r][q][pswz]
    int bx = blockIdx.x;                   // t*128 + chq
    int t = bx >> 7, chq = bx & 127;
    int b0 = blockIdx.y * 16;
    const float* x = (t == 0) ? x1 : (t == 1) ? x3 : x5;
    int w = threadIdx.x >> 6, lane = threadIdx.x & 63;
    int bkt0 = t * CC + chq * 4;

    int E0 = cnt[bkt0 + 0]; if (E0 > CAP) E0 = CAP;
    int E1 = cnt[bkt0 + 1]; if (E1 > CAP) E1 = CAP;
    int E2 = cnt[bkt0 + 2]; if (E2 > CAP) E2 = CAP;
    int E3 = cnt[bkt0 + 3]; if (E3 > CAP) E3 = CAP;
    if ((E0 | E1 | E2 | E3) == 0) return;

    // preload all bucket words (coalesced; drained by the barrier)
    u32 pk0[4], pk1[4];
#pragma unroll
    for (int q = 0; q < 4; ++q) {
        pk0[q] = bucket[(bkt0 + q) * CAP + lane];
        pk1[q] = bucket[(bkt0 + q) * CAP + 64 + lane];
    }

    // stage: wave w covers rows r = w*4 .. w*4+3, q = 0..3 -> 16 DMAs of 1KB,
    // consecutive (r,q) = consecutive 1KB of a 4KB contiguous span
#pragma unroll
    for (int j = 0; j < 16; ++j) {
        int idx = w * 16 + j;
        int r = idx >> 2, q = idx & 3;
        const float* src = x + ((size_t)(b0 + r) * CC + chq * 4 + q) * PIX
                             + ((lane ^ r) << 2);          // 16B-chunk XOR swizzle
        GLOAD_LDS16(src, &ldsf[(r * 4 + q) * 256]);
    }
    __syncthreads();

    // scatter: 4 entries per wave-instr (sub = entry slot, bl = local b)
    int sub = lane >> 4, bl = lane & 15;
#pragma unroll
    for (int q = 0; q < 4; ++q) {
        int Eq = (q == 0) ? E0 : (q == 1) ? E1 : (q == 2) ? E2 : E3;
        for (int e4 = w * 4; e4 < Eq; e4 += 16) {
            int e = e4 + sub;
            u32 w0 = __shfl(pk0[q], e & 63);
            u32 w1 = __shfl(pk1[q], e & 63);
            u32 word = (e < 64) ? w0 : w1;
            if (e < Eq) {
                u32 rowhw = word >> 8;
                int p = (int)(word & 255);
                float f = ldsf[(bl * 4 + q) * 256 + ((((p >> 2) ^ bl) << 2) | (p & 3))];
                fT[(size_t)rowhw * BB + b0 + bl] = (__bf16)f;
            }
        }
    }
}

__global__ __launch_bounds__(256) void ftrans_kernel(const __bf16* __restrict__ fT,
                                                     __bf16* __restrict__ feats) {
    __shared__ __bf16 lds[64 * 128];
    int hw = blockIdx.x;
    int c0 = blockIdx.y * 64;
    int t = threadIdx.x;
    int l16 = t & 15;
#pragma unroll
    for (int r4 = 0; r4 < 4; ++r4) {
        int cr = (t >> 4) + r4 * 16;
        bf16x8 v = *(const bf16x8*)(fT + ((size_t)(c0 + cr) * HW2 + hw) * BB + l16 * 8);
        int chunk = l16 ^ ((cr >> 3) & 7);
        *(bf16x8*)&lds[cr * 128 + chunk * 8] = v;
    }
    __syncthreads();
    int cg = t & 7;
#pragma unroll
    for (int r = 0; r < 4; ++r) {
        int b = (t >> 3) + r * 32;
        bf16x8 ov;
#pragma unroll
        for (int k = 0; k < 8; ++k) {
            int c = cg * 8 + k;
            ov[k] = lds[c * 128 + (((b >> 3) ^ cg) * 8) + (b & 7)];
        }
        *(bf16x8*)(feats + ((size_t)b * HW2 + hw) * NC + c0 + cg * 8) = ov;
    }
}

// GEMM: m97 structure, 128x128 tile, BK=64, XOR-swizzled LDS via pre-swizzled source.
__global__ __launch_bounds__(256) void gemm_kernel(const __bf16* __restrict__ feats,
                                                   const __bf16* __restrict__ Wb,
                                                   float* __restrict__ out) {
    __shared__ __bf16 ldsbuf[16384];           // A [128][64] @0, B [128][64] @8192
    __bf16* Abuf = ldsbuf;
    __bf16* Bbuf = ldsbuf + 8192;

    const int d = blockIdx.x;                  // 1176 blocks, 147 per XCD
    const int wg = (d & 7) * 147 + (d >> 3);
    const int o_base = (wg % 6) * 128;
    const int m_base = (wg / 6) * 128;

    const int tid = threadIdx.x;
    const int wave = tid >> 6, lane = tid & 63;
    const int wo = wave >> 1, wm = wave & 1;
    const int l15 = lane & 15, g = lane >> 4;
    const int xr = l15 & 7;

    f32x4 acc[4][4] = {};

    for (int kt = 0; kt < 6; ++kt) {
        const int k0g = kt * 64;
#pragma unroll
        for (int it = 0; it < 4; ++it) {
            int ck = tid + it * 256;
            int row = ck >> 3, cc = ck & 7;
            int koff = k0g + ((cc ^ (row & 7)) << 3);
            GLOAD_LDS16(Wb    + (size_t)(o_base + row) * NC + koff, Abuf + ck * 8);
            GLOAD_LDS16(feats + (size_t)(m_base + row) * NC + koff, Bbuf + ck * 8);
        }
        __syncthreads();
#pragma unroll
        for (int k0 = 0; k0 < 64; k0 += 32) {
            const int cb = (k0 >> 3) + g;
            bf16x8 a[4], b[4];
#pragma unroll
            for (int s = 0; s < 4; ++s) {
                int arow = wo * 64 + s * 16 + l15;
                a[s] = *(const bf16x8*)&Abuf[arow * 64 + ((cb ^ xr) << 3)];
                int brow = wm * 64 + s * 16 + l15;
                b[s] = *(const bf16x8*)&Bbuf[brow * 64 + ((cb ^ xr) << 3)];
            }
#pragma unroll
            for (int os = 0; os < 4; ++os)
#pragma unroll
                for (int ms = 0; ms < 4; ++ms)
                    acc[os][ms] = __builtin_amdgcn_mfma_f32_16x16x32_bf16(a[os], b[ms], acc[os][ms], 0, 0, 0);
        }
        __syncthreads();
    }

#pragma unroll
    for (int os = 0; os < 4; ++os)
#pragma unroll
        for (int ms = 0; ms < 4; ++ms) {
            int m = m_base + wm * 64 + ms * 16 + l15;
            int bb = m / HW2;
            int hw = m - bb * HW2;
            int o = o_base + wo * 64 + os * 16 + g * 4;
            float* dst = out + ((size_t)bb * NO + o) * HW2 + hw;
            f32x4 v = acc[os][ms];
            dst[0 * HW2] = v[0];
            dst[1 * HW2] = v[1];
            dst[2 * HW2] = v[2];
            dst[3 * HW2] = v[3];
        }
}

extern "C" void kernel_launch(void* const* d_in, const int* in_sizes, int n_in,
                              void* d_out, int out_size, void* d_ws, size_t ws_size,
                              hipStream_t stream) {
    const float* x1   = (const float*)d_in[0];
    const float* x3   = (const float*)d_in[1];
    const float* x5   = (const float*)d_in[2];
    const float* W    = (const float*)d_in[3];
    const int*   idx  = (const int*)d_in[4];
    const int*   offh = (const int*)d_in[5];
    const int*   offw = (const int*)d_in[6];
    float* out = (float*)d_out;

    char* ws = (char*)d_ws;
    __bf16* fT     = (__bf16*)(ws);              // 19,267,584 B
    __bf16* feats  = (__bf16*)(ws + 19267584);   // 19,267,584 B
    __bf16* Wb     = (__bf16*)(ws + 38535168);   // 589,824 B
    int*    cnt    = (int*)   (ws + 39124992);   // 6,144 B
    u32*    bucket = (u32*)   (ws + 39131136);   // 786,432 B

    wconv_kernel<<<(NO * NC) / 256, 256, 0, stream>>>(W, Wb);
    hipMemsetAsync(cnt, 0, 1536 * sizeof(int), stream);
    fill_kernel<<<(NC * HW2) / 256, 256, 0, stream>>>(idx, offh, offw, cnt, bucket);
    scatter_kernel<<<dim3(384, 8), 256, 0, stream>>>(x1, x3, x5, cnt, bucket, fT);
    ftrans_kernel<<<dim3(HW2, 6), 256, 0, stream>>>(fT, feats);
    gemm_kernel<<<1176, 256, 0, stream>>>(feats, Wb, out);
}

// Round 10
// 107.718 us; speedup vs baseline: 1.0775x; 1.0775x over previous
//
#include <hip/hip_runtime.h>
#include <hip/hip_bf16.h>

#define PIX 256
#define CROP 14
#define HW2 196
#define BB 128
#define CC 512
#define NC 384
#define NO 768
#define CAP 128
#define ENT_T 25088   // entries per tensor t = 128*196

typedef __bf16 bf16x8 __attribute__((ext_vector_type(8)));
typedef __bf16 bf16x4 __attribute__((ext_vector_type(4)));
typedef float  f32x4  __attribute__((ext_vector_type(4)));
typedef unsigned int u32;

#define GLOAD_LDS16(src, dst) \
    __builtin_amdgcn_global_load_lds((const __attribute__((address_space(1))) void*)(src), \
                                     (__attribute__((address_space(3))) void*)(dst), 16, 0, 0)

__global__ void wconv_kernel(const float* __restrict__ W, __bf16* __restrict__ Wb) {
    int tid = blockIdx.x * 256 + threadIdx.x;
    Wb[tid] = (__bf16)W[tid];
}

// entry word: (c3loc<<25) | (hw<<17) | (p<<9) | ch   (7+8+8+9 = 32 bits)
__global__ void fill_kernel(const int* __restrict__ idx, const int* __restrict__ offh,
                            const int* __restrict__ offw, int* __restrict__ cnt,
                            u32* __restrict__ bucket) {
    int tid = blockIdx.x * 256 + threadIdx.x;   // < 75264
    int c3 = tid / HW2;
    int hw = tid - c3 * HW2;
    int i = hw / CROP, j = hw - i * CROP;
    int p = (offh[c3] + i) * 16 + offw[c3] + j;
    int ch = idx[c3 * PIX + p];
    int bkt = (c3 >> 7) * CC + ch;              // t*512 + ch
    int pos = atomicAdd(&cnt[bkt], 1);
    if (pos < CAP)
        bucket[bkt * CAP + pos] =
            ((u32)(c3 & 127) << 25) | ((u32)hw << 17) | ((u32)p << 9) | (u32)ch;
}

// exclusive prefix over 1536 clamped counts (single block)
__global__ __launch_bounds__(256) void scan_kernel(const int* __restrict__ cnt,
                                                   int* __restrict__ pref) {
    __shared__ int part[256];
    int tid = threadIdx.x;
    int loc[6];
    int s = 0;
#pragma unroll
    for (int i = 0; i < 6; ++i) {
        int v = cnt[tid * 6 + i]; if (v > CAP) v = CAP;
        loc[i] = s; s += v;
    }
    part[tid] = s;
    __syncthreads();
    if (tid < 64) {
        int l4[4]; int s4 = 0;
#pragma unroll
        for (int i = 0; i < 4; ++i) { l4[i] = s4; s4 += part[tid * 4 + i]; }
        int v = s4;
#pragma unroll
        for (int d = 1; d < 64; d <<= 1) { int u = __shfl_up(v, d); if (tid >= d) v += u; }
        int excl = v - s4;
#pragma unroll
        for (int i = 0; i < 4; ++i) part[tid * 4 + i] = excl + l4[i];
    }
    __syncthreads();
    int off = part[tid];
#pragma unroll
    for (int i = 0; i < 6; ++i) pref[tid * 6 + i] = off + loc[i];
}

// dense, ch-ascending entry list per t
__global__ __launch_bounds__(128) void compact_kernel(const int* __restrict__ cnt,
                                                      const int* __restrict__ pref,
                                                      const u32* __restrict__ bucket,
                                                      u32* __restrict__ ent) {
    int bkt = blockIdx.x;
    int E = cnt[bkt]; if (E > CAP) E = CAP;
    int tid = threadIdx.x;
    if (tid < E) ent[pref[bkt] + tid] = bucket[bkt * CAP + tid];
}

// scatter v7: block = (b, t). Sequential sweep of contiguous 512KB window
// x_t[b] (entries sorted by ch), scatter into LDS feats_local[hw][c3loc]
// (each cell written exactly once), then stream out to feats directly.
// No fT, no ftrans.
__global__ __launch_bounds__(256) void scatter_kernel(
        const float* __restrict__ x1, const float* __restrict__ x3,
        const float* __restrict__ x5, const u32* __restrict__ ent,
        __bf16* __restrict__ feats) {
    __shared__ __bf16 fl[HW2 * 128];         // 50176 B -> 3 blocks/CU
    int blk = blockIdx.x;                    // b*3 + t
    int b = blk / 3;
    int t = blk - b * 3;
    const float* x = (t == 0) ? x1 : (t == 1) ? x3 : x5;
    const float* xb = x + (size_t)b * CC * PIX;
    const u32* el = ent + t * ENT_T;
    int tid = threadIdx.x;

#pragma unroll 4
    for (int g = tid; g < ENT_T; g += 256) {
        u32 wd = el[g];                      // coalesced, ascending ch
        int ch = wd & 511;
        int p  = (wd >> 9) & 255;
        int hw = (wd >> 17) & 255;
        int c3 = wd >> 25;
        float f = xb[ch * PIX + p];          // sequential-window demand read
        fl[hw * 128 + c3] = (__bf16)f;
    }
    __syncthreads();

    // stream out: feats[(b*196+hw)][t*128 + c] — 256B per hw row
    const size_t obase = (size_t)b * HW2 * NC + (size_t)t * 128;
#pragma unroll 4
    for (int i2 = tid; i2 < HW2 * 32; i2 += 256) {
        int hw = i2 >> 5, cq = (i2 & 31) * 4;
        *(bf16x4*)(feats + obase + (size_t)hw * NC + cq) = *(const bf16x4*)&fl[hw * 128 + cq];
    }
}

// GEMM: m97 structure, 128x128 tile, BK=64, XOR-swizzled LDS via pre-swizzled source.
__global__ __launch_bounds__(256) void gemm_kernel(const __bf16* __restrict__ feats,
                                                   const __bf16* __restrict__ Wb,
                                                   float* __restrict__ out) {
    __shared__ __bf16 ldsbuf[16384];           // A [128][64] @0, B [128][64] @8192
    __bf16* Abuf = ldsbuf;
    __bf16* Bbuf = ldsbuf + 8192;

    const int d = blockIdx.x;                  // 1176 blocks, 147 per XCD
    const int wg = (d & 7) * 147 + (d >> 3);
    const int o_base = (wg % 6) * 128;
    const int m_base = (wg / 6) * 128;

    const int tid = threadIdx.x;
    const int wave = tid >> 6, lane = tid & 63;
    const int wo = wave >> 1, wm = wave & 1;
    const int l15 = lane & 15, g = lane >> 4;
    const int xr = l15 & 7;

    f32x4 acc[4][4] = {};

    for (int kt = 0; kt < 6; ++kt) {
        const int k0g = kt * 64;
#pragma unroll
        for (int it = 0; it < 4; ++it) {
            int ck = tid + it * 256;
            int row = ck >> 3, cc = ck & 7;
            int koff = k0g + ((cc ^ (row & 7)) << 3);
            GLOAD_LDS16(Wb    + (size_t)(o_base + row) * NC + koff, Abuf + ck * 8);
            GLOAD_LDS16(feats + (size_t)(m_base + row) * NC + koff, Bbuf + ck * 8);
        }
        __syncthreads();
#pragma unroll
        for (int k0 = 0; k0 < 64; k0 += 32) {
            const int cb = (k0 >> 3) + g;
            bf16x8 a[4], b[4];
#pragma unroll
            for (int s = 0; s < 4; ++s) {
                int arow = wo * 64 + s * 16 + l15;
                a[s] = *(const bf16x8*)&Abuf[arow * 64 + ((cb ^ xr) << 3)];
                int brow = wm * 64 + s * 16 + l15;
                b[s] = *(const bf16x8*)&Bbuf[brow * 64 + ((cb ^ xr) << 3)];
            }
#pragma unroll
            for (int os = 0; os < 4; ++os)
#pragma unroll
                for (int ms = 0; ms < 4; ++ms)
                    acc[os][ms] = __builtin_amdgcn_mfma_f32_16x16x32_bf16(a[os], b[ms], acc[os][ms], 0, 0, 0);
        }
        __syncthreads();
    }

#pragma unroll
    for (int os = 0; os < 4; ++os)
#pragma unroll
        for (int ms = 0; ms < 4; ++ms) {
            int m = m_base + wm * 64 + ms * 16 + l15;
            int bb = m / HW2;
            int hw = m - bb * HW2;
            int o = o_base + wo * 64 + os * 16 + g * 4;
            float* dst = out + ((size_t)bb * NO + o) * HW2 + hw;
            f32x4 v = acc[os][ms];
            dst[0 * HW2] = v[0];
            dst[1 * HW2] = v[1];
            dst[2 * HW2] = v[2];
            dst[3 * HW2] = v[3];
        }
}

extern "C" void kernel_launch(void* const* d_in, const int* in_sizes, int n_in,
                              void* d_out, int out_size, void* d_ws, size_t ws_size,
                              hipStream_t stream) {
    const float* x1   = (const float*)d_in[0];
    const float* x3   = (const float*)d_in[1];
    const float* x5   = (const float*)d_in[2];
    const float* W    = (const float*)d_in[3];
    const int*   idx  = (const int*)d_in[4];
    const int*   offh = (const int*)d_in[5];
    const int*   offw = (const int*)d_in[6];
    float* out = (float*)d_out;

    char* ws = (char*)d_ws;
    __bf16* feats  = (__bf16*)(ws);              // 19,267,584 B
    __bf16* Wb     = (__bf16*)(ws + 19267584);   // 589,824 B
    int*    cnt    = (int*)   (ws + 19857408);   // 6,144 B
    int*    pref   = (int*)   (ws + 19863552);   // 6,144 B
    u32*    bucket = (u32*)   (ws + 19869696);   // 786,432 B
    u32*    ent    = (u32*)   (ws + 20656128);   // 301,056 B

    wconv_kernel<<<(NO * NC) / 256, 256, 0, stream>>>(W, Wb);
    hipMemsetAsync(cnt, 0, 1536 * sizeof(int), stream);
    fill_kernel<<<(NC * HW2) / 256, 256, 0, stream>>>(idx, offh, offw, cnt, bucket);
    scan_kernel<<<1, 256, 0, stream>>>(cnt, pref);
    compact_kernel<<<1536, 128, 0, stream>>>(cnt, pref, bucket, ent);
    scatter_kernel<<<384, 256, 0, stream>>>(x1, x3, x5, ent, feats);
    gemm_kernel<<<1176, 256, 0, stream>>>(feats, Wb, out);
}